// Round 1
// baseline (532.562 us; speedup 1.0000x reference)
//
#include <hip/hip_runtime.h>
#include <stdint.h>

#define NB 32        // batch size B (fixed by problem)
#define SCAN_T 256   // threads per scan block
#define SCAN_E 1024  // elements per scan block (4 per thread)

// ---------------------------------------------------------------------------
// x (B, N) -> xt (N, B): 32x32 LDS tile transpose, coalesced read and write.
// ---------------------------------------------------------------------------
__global__ void transpose_x_kernel(const float* __restrict__ x,
                                   float* __restrict__ xt, int N) {
    __shared__ float tile[32][33];  // +1 pad: avoid bank conflicts
    int n0 = blockIdx.x * 32;
    for (int i = threadIdx.y; i < 32; i += 8) {
        int n = n0 + threadIdx.x;
        tile[i][threadIdx.x] = (n < N) ? x[(size_t)i * N + n] : 0.f;
    }
    __syncthreads();
    for (int i = threadIdx.y; i < 32; i += 8) {
        int n = n0 + i;
        if (n < N) xt[(size_t)n * NB + threadIdx.x] = tile[threadIdx.x][i];
    }
}

// ---------------------------------------------------------------------------
// Histogram: deg[m] = number of edges with dst == m.
// ---------------------------------------------------------------------------
__global__ void hist_kernel(const int* __restrict__ dst,
                            int* __restrict__ deg, int nnz) {
    int e = blockIdx.x * blockDim.x + threadIdx.x;
    if (e < nnz) atomicAdd(&deg[dst[e]], 1);
}

// ---------------------------------------------------------------------------
// Scan stage 1: per-block sums of deg (SCAN_E elems / block).
// ---------------------------------------------------------------------------
__global__ void scan_block_sums(const int* __restrict__ deg,
                                int* __restrict__ bsum, int M) {
    __shared__ int sdata[SCAN_T];
    int t = threadIdx.x;
    int base = blockIdx.x * SCAN_E + t * 4;
    int s = 0;
#pragma unroll
    for (int k = 0; k < 4; ++k) {
        int m = base + k;
        if (m < M) s += deg[m];
    }
    sdata[t] = s;
    __syncthreads();
    for (int off = SCAN_T / 2; off > 0; off >>= 1) {
        if (t < off) sdata[t] += sdata[t + off];
        __syncthreads();
    }
    if (t == 0) bsum[blockIdx.x] = sdata[0];
}

// ---------------------------------------------------------------------------
// Scan stage 2: exclusive scan of block sums (single block, nblk <= 256).
// ---------------------------------------------------------------------------
__global__ void scan_top(int* __restrict__ bsum, int nblk) {
    __shared__ int sdata[256];
    int t = threadIdx.x;
    int v = (t < nblk) ? bsum[t] : 0;
    sdata[t] = v;
    __syncthreads();
    for (int off = 1; off < 256; off <<= 1) {
        int add = (t >= off) ? sdata[t - off] : 0;
        __syncthreads();
        sdata[t] += add;
        __syncthreads();
    }
    if (t < nblk) bsum[t] = sdata[t] - v;  // inclusive - self = exclusive
}

// ---------------------------------------------------------------------------
// Scan stage 3: exclusive scan within each block + block offset ->
// rowptr[m] (list start) and cursor[m] (fill pointer, starts == rowptr).
// ---------------------------------------------------------------------------
__global__ void scan_write(const int* __restrict__ deg,
                           const int* __restrict__ bsum,
                           int* __restrict__ rowptr,
                           int* __restrict__ cursor, int M) {
    __shared__ int sthr[SCAN_T];
    int t = threadIdx.x;
    int base = blockIdx.x * SCAN_E + t * 4;
    int d[4];
    int s = 0;
#pragma unroll
    for (int k = 0; k < 4; ++k) {
        int m = base + k;
        d[k] = (m < M) ? deg[m] : 0;
        s += d[k];
    }
    sthr[t] = s;
    __syncthreads();
    for (int off = 1; off < SCAN_T; off <<= 1) {
        int add = (t >= off) ? sthr[t - off] : 0;
        __syncthreads();
        sthr[t] += add;
        __syncthreads();
    }
    int run = bsum[blockIdx.x] + (sthr[t] - s);  // exclusive prefix for this thread
#pragma unroll
    for (int k = 0; k < 4; ++k) {
        int m = base + k;
        if (m < M) {
            rowptr[m] = run;
            cursor[m] = run;
            run += d[k];
        }
    }
}

// ---------------------------------------------------------------------------
// Fill CSR: claim a slot in dst's list, write packed (src, val_bits) 8B entry.
// ---------------------------------------------------------------------------
__global__ void fill_kernel(const int* __restrict__ src,
                            const int* __restrict__ dst,
                            const float* __restrict__ vals,
                            int* __restrict__ cursor,
                            int2* __restrict__ csr, int nnz) {
    int e = blockIdx.x * blockDim.x + threadIdx.x;
    if (e >= nnz) return;
    int d = dst[e];
    int p = atomicAdd(&cursor[d], 1);
    csr[p] = make_int2(src[e], __float_as_int(vals[e]));
}

// ---------------------------------------------------------------------------
// Pull gather: one half-wave (32 lanes = 32 batch values) per output row m.
// Walks the contiguous edge list [rowptr[m], cursor[m]) — after fill,
// cursor[m] == rowptr[m] + deg[m]. Register accumulation, single coalesced
// 128B store per row. No atomics.
// ---------------------------------------------------------------------------
__global__ void gather_kernel(const int* __restrict__ rowptr,
                              const int* __restrict__ rowend,
                              const int2* __restrict__ csr,
                              const float* __restrict__ xt,
                              float* __restrict__ yt, int M) {
    int g = threadIdx.x >> 5;                     // half-wave group (0..7)
    int b = threadIdx.x & 31;                     // batch lane
    int m = blockIdx.x * (blockDim.x >> 5) + g;
    if (m >= M) return;
    int j = rowptr[m];
    int end = rowend[m];
    float acc = 0.f;
    // 4-wide unroll: 4 independent xt loads in flight per step
    for (; j + 4 <= end; j += 4) {
        int2 p0 = csr[j];
        int2 p1 = csr[j + 1];
        int2 p2 = csr[j + 2];
        int2 p3 = csr[j + 3];
        float x0 = xt[(size_t)p0.x * NB + b];
        float x1 = xt[(size_t)p1.x * NB + b];
        float x2 = xt[(size_t)p2.x * NB + b];
        float x3 = xt[(size_t)p3.x * NB + b];
        acc = fmaf(__int_as_float(p0.y), x0, acc);
        acc = fmaf(__int_as_float(p1.y), x1, acc);
        acc = fmaf(__int_as_float(p2.y), x2, acc);
        acc = fmaf(__int_as_float(p3.y), x3, acc);
    }
    for (; j < end; ++j) {
        int2 p = csr[j];
        acc = fmaf(__int_as_float(p.y), xt[(size_t)p.x * NB + b], acc);
    }
    yt[(size_t)m * NB + b] = acc;
}

// ---------------------------------------------------------------------------
// yt (M, B) -> out (B, M), + bias: 32x32 LDS tile transpose.
// ---------------------------------------------------------------------------
__global__ void finalize_kernel(const float* __restrict__ yt,
                                const float* __restrict__ bias,
                                float* __restrict__ out, int M) {
    __shared__ float tile[32][33];
    int m0 = blockIdx.x * 32;
    for (int i = threadIdx.y; i < 32; i += 8) {
        int m = m0 + i;
        tile[i][threadIdx.x] = (m < M) ? yt[(size_t)m * NB + threadIdx.x] : 0.f;
    }
    __syncthreads();
    for (int i = threadIdx.y; i < 32; i += 8) {
        int m = m0 + threadIdx.x;
        if (m < M) out[(size_t)i * M + m] = tile[threadIdx.x][i] + bias[m];
    }
}

extern "C" void kernel_launch(void* const* d_in, const int* in_sizes, int n_in,
                              void* d_out, int out_size, void* d_ws, size_t ws_size,
                              hipStream_t stream) {
    const float* x       = (const float*)d_in[0];   // (B, N, 1) fp32
    const int*   indices = (const int*)  d_in[1];   // (2, NNZ) int32
    const float* vals    = (const float*)d_in[2];   // (NNZ,) fp32
    const float* bias    = (const float*)d_in[3];   // (M, 1) fp32

    float* out = (float*)d_out;                     // (B, M, 1) fp32

    int nnz = in_sizes[1] / 2;
    int N   = in_sizes[0] / NB;
    int M   = in_sizes[3];

    const int* src = indices;        // row 0
    const int* dst = indices + nnz;  // row 1

    // workspace layout:
    //   xt      N*NB f32   (12.8 MB)
    //   yt      M*NB f32   (12.8 MB)
    //   deg     M   i32    (0.4 MB)
    //   rowptr  M   i32    (0.4 MB)
    //   cursor  M   i32    (0.4 MB)
    //   bsum    1024 i32
    //   csr     NNZ int2   (25.6 MB)
    float* xt     = (float*)d_ws;
    float* yt     = xt + (size_t)N * NB;
    int*   deg    = (int*)(yt + (size_t)M * NB);
    int*   rowptr = deg + M;
    int*   cursor = rowptr + M;
    int*   bsum   = cursor + M;
    int2*  csr    = (int2*)(((uintptr_t)(bsum + 1024) + 15) & ~(uintptr_t)15);

    transpose_x_kernel<<<(N + 31) / 32, dim3(32, 8), 0, stream>>>(x, xt, N);

    hipMemsetAsync(deg, 0, (size_t)M * sizeof(int), stream);

    int egrid = (nnz + 255) / 256;
    hist_kernel<<<egrid, 256, 0, stream>>>(dst, deg, nnz);

    int nblk = (M + SCAN_E - 1) / SCAN_E;  // 98 for M=100000; must be <= 256
    scan_block_sums<<<nblk, SCAN_T, 0, stream>>>(deg, bsum, M);
    scan_top<<<1, 256, 0, stream>>>(bsum, nblk);
    scan_write<<<nblk, SCAN_T, 0, stream>>>(deg, bsum, rowptr, cursor, M);

    fill_kernel<<<egrid, 256, 0, stream>>>(src, dst, vals, cursor, csr, nnz);

    // after fill, cursor[m] == rowptr[m] + deg[m] == list end
    int mpb = 256 / 32;  // rows per block
    gather_kernel<<<(M + mpb - 1) / mpb, 256, 0, stream>>>(rowptr, cursor, csr,
                                                           xt, yt, M);

    finalize_kernel<<<(M + 31) / 32, dim3(32, 8), 0, stream>>>(yt, bias, out, M);
}